// Round 1
// baseline (579.687 us; speedup 1.0000x reference)
//
#include <hip/hip_runtime.h>

#define N_NODES 100000
#define N_EDGES 1600000
#define DIM     128
#define EPS_BN  1e-5f

// ---------------------------------------------------------------------------
// edge_index dtype detector: if data is int64 (little-endian, values < 2^31),
// every odd int32 word (high half) is 0. 64 random int32 indices in [0,1e5)
// being all zero has p ~ 1e-320 -> safe discriminator. flag=1 => int64.
// ---------------------------------------------------------------------------
__global__ void detect_dtype(const int* raw, int* flag) {
    long long s = 0;
    for (int k = 0; k < 64; ++k) s += raw[2 * k + 1];
    *flag = (s == 0) ? 1 : 0;
}

__device__ __forceinline__ int load_row(const void* eidx, int is64, int e) {
    if (is64) return (int)((const long long*)eidx)[e];
    return ((const int*)eidx)[e];
}
__device__ __forceinline__ int load_col(const void* eidx, int is64, int e) {
    if (is64) return (int)((const long long*)eidx)[N_EDGES + e];
    return ((const int*)eidx)[N_EDGES + e];
}

// ---------------------------------------------------------------------------
// CSR build: histogram -> block scan -> scan of block sums -> add offsets
// ---------------------------------------------------------------------------
__global__ void hist_kernel(const void* eidx, const int* flag, int* counts) {
    int is64 = *flag;
    for (int e = blockIdx.x * blockDim.x + threadIdx.x; e < N_EDGES;
         e += gridDim.x * blockDim.x) {
        atomicAdd(&counts[load_row(eidx, is64, e)], 1);
    }
}

__global__ void scan_block(const int* in, int* excl, int* bsums, int n) {
    __shared__ int tmp[256];
    int i = blockIdx.x * 256 + threadIdx.x;
    int v = (i < n) ? in[i] : 0;
    tmp[threadIdx.x] = v;
    __syncthreads();
    for (int off = 1; off < 256; off <<= 1) {
        int t = (threadIdx.x >= off) ? tmp[threadIdx.x - off] : 0;
        __syncthreads();
        tmp[threadIdx.x] += t;
        __syncthreads();
    }
    if (i < n) excl[i] = tmp[threadIdx.x] - v;   // exclusive within block
    if (threadIdx.x == 255) bsums[blockIdx.x] = tmp[255];
}

__global__ void scan_sums(int* bsums, int nb) {   // nb <= 512, single block
    __shared__ int tmp[512];
    int v = ((int)threadIdx.x < nb) ? bsums[threadIdx.x] : 0;
    tmp[threadIdx.x] = v;
    __syncthreads();
    for (int off = 1; off < 512; off <<= 1) {
        int t = (threadIdx.x >= off) ? tmp[threadIdx.x - off] : 0;
        __syncthreads();
        tmp[threadIdx.x] += t;
        __syncthreads();
    }
    if ((int)threadIdx.x < nb) bsums[threadIdx.x] = tmp[threadIdx.x] - v;
}

__global__ void scan_add(const int* excl, const int* bsums, int* row_start,
                         int* cursor, int n, int total) {
    int i = blockIdx.x * 256 + threadIdx.x;
    if (i < n) {
        int v = excl[i] + bsums[blockIdx.x];
        row_start[i] = v;
        cursor[i] = v;
    }
    if (i == 0) row_start[n] = total;
}

__global__ void fill_kernel(const void* eidx, const int* flag, int* cursor,
                            int* cols) {
    int is64 = *flag;
    for (int e = blockIdx.x * blockDim.x + threadIdx.x; e < N_EDGES;
         e += gridDim.x * blockDim.x) {
        int r = load_row(eidx, is64, e);
        int c = load_col(eidx, is64, e);
        int pos = atomicAdd(&cursor[r], 1);
        cols[pos] = c;
    }
}

// ---------------------------------------------------------------------------
// Aggregation + residual: H[n] = x[n] + sum_{c in nbrs(n)} x[c]
// One wave per node; lane holds float2 (64 lanes * 8B = full 512B row).
// Neighbor indices pre-loaded cooperatively (deg<=64 in one coalesced load),
// broadcast via __shfl.
// ---------------------------------------------------------------------------
__global__ void agg_kernel(const float* __restrict__ x,
                           const int* __restrict__ row_start,
                           const int* __restrict__ cols,
                           float* __restrict__ H) {
    int wave = threadIdx.x >> 6;
    int lane = threadIdx.x & 63;
    int node = blockIdx.x * 4 + wave;
    if (node >= N_NODES) return;
    float2 acc = ((const float2*)(x + (size_t)node * DIM))[lane];
    int s = row_start[node], e = row_start[node + 1];
    int deg = e - s;
    int c_l = (s + lane < e) ? cols[s + lane] : 0;
    int dmain = deg < 64 ? deg : 64;
    for (int j = 0; j < dmain; ++j) {
        int c = __shfl(c_l, j);
        float2 v = ((const float2*)(x + (size_t)c * DIM))[lane];
        acc.x += v.x; acc.y += v.y;
    }
    for (int j = s + 64; j < e; ++j) {           // deg>64 tail (vanishingly rare)
        int c = cols[j];
        float2 v = ((const float2*)(x + (size_t)c * DIM))[lane];
        acc.x += v.x; acc.y += v.y;
    }
    ((float2*)(H + (size_t)node * DIM))[lane] = acc;
}

// ---------------------------------------------------------------------------
// Vector-f32 GEMM, in-place on H: H = act(H @ W + b), 80-row tiles (1250
// blocks exactly), W streamed through LDS in 4 k-chunks of 32. Thread tile:
// 10 rows x 4 cols (float4). STATS fuses BN column sum/sumsq reduction.
// LDS: 40960 (Hs) + 16384 (Ws) + 1024 (stats) = 58368B -> 2 blocks/CU.
// ---------------------------------------------------------------------------
template <bool RELU, bool STATS>
__global__ __launch_bounds__(256) void gemm_kernel(float* __restrict__ H,
                                                   const float* __restrict__ W,
                                                   const float* __restrict__ b,
                                                   float* __restrict__ stats) {
    __shared__ float Hs[80 * DIM];
    __shared__ float Ws[32 * DIM];
    __shared__ float csum[DIM], csq[DIM];
    int t = threadIdx.x;
    int row0 = blockIdx.x * 80;

    const float4* Hg = (const float4*)(H + (size_t)row0 * DIM);
    float4* Hs4 = (float4*)Hs;
#pragma unroll
    for (int i = 0; i < 10; ++i) Hs4[t + 256 * i] = Hg[t + 256 * i];
    if (STATS && t < DIM) { csum[t] = 0.f; csq[t] = 0.f; }

    int tj = t & 31, tr = t >> 5;
    float4 acc[10];
    float4 bb = ((const float4*)b)[tj];
#pragma unroll
    for (int m = 0; m < 10; ++m) acc[m] = bb;

    float4* Ws4 = (float4*)Ws;
    for (int kb = 0; kb < 4; ++kb) {
        __syncthreads();
        const float4* Wg = (const float4*)(W + kb * 32 * DIM);
#pragma unroll
        for (int i = 0; i < 4; ++i) Ws4[t + 256 * i] = Wg[t + 256 * i];
        __syncthreads();
#pragma unroll 4
        for (int k = 0; k < 32; ++k) {
            float4 w = Ws4[k * 32 + tj];
            int kk = kb * 32 + k;
#pragma unroll
            for (int m = 0; m < 10; ++m) {
                float h = Hs[(tr + 8 * m) * DIM + kk];
                acc[m].x += h * w.x; acc[m].y += h * w.y;
                acc[m].z += h * w.z; acc[m].w += h * w.w;
            }
        }
    }

    float4* Ho = (float4*)(H + (size_t)row0 * DIM);
    float4 s4 = {0.f, 0.f, 0.f, 0.f}, q4 = {0.f, 0.f, 0.f, 0.f};
#pragma unroll
    for (int m = 0; m < 10; ++m) {
        float4 v = acc[m];
        if (RELU) {
            v.x = fmaxf(v.x, 0.f); v.y = fmaxf(v.y, 0.f);
            v.z = fmaxf(v.z, 0.f); v.w = fmaxf(v.w, 0.f);
        }
        Ho[(tr + 8 * m) * 32 + tj] = v;
        if (STATS) {
            s4.x += v.x; s4.y += v.y; s4.z += v.z; s4.w += v.w;
            q4.x += v.x * v.x; q4.y += v.y * v.y;
            q4.z += v.z * v.z; q4.w += v.w * v.w;
        }
    }
    if (STATS) {
        atomicAdd(&csum[4 * tj + 0], s4.x); atomicAdd(&csum[4 * tj + 1], s4.y);
        atomicAdd(&csum[4 * tj + 2], s4.z); atomicAdd(&csum[4 * tj + 3], s4.w);
        atomicAdd(&csq[4 * tj + 0], q4.x);  atomicAdd(&csq[4 * tj + 1], q4.y);
        atomicAdd(&csq[4 * tj + 2], q4.z);  atomicAdd(&csq[4 * tj + 3], q4.w);
        __syncthreads();
        if (t < DIM) {
            atomicAdd(&stats[t], csum[t]);
            atomicAdd(&stats[DIM + t], csq[t]);
        }
    }
}

__global__ void finalize_stats(float* stats, const float* gamma,
                               const float* beta) {
    int t = threadIdx.x;                         // 128 threads
    float mean = stats[t] * (1.0f / N_NODES);
    float m2 = stats[DIM + t] * (1.0f / N_NODES);
    float var = m2 - mean * mean;                // biased, as torch BN
    float inv = rsqrtf(var + EPS_BN);
    float sc = gamma[t] * inv;
    float sh = beta[t] - mean * sc;
    stats[t] = sc;                               // own-slot overwrite: safe
    stats[DIM + t] = sh;
}

__global__ void bn_apply(const float* __restrict__ H,
                         const float* __restrict__ stats,
                         float* __restrict__ out) {
    int i = blockIdx.x * 256 + threadIdx.x;      // exactly N*DIM/4 threads
    int j4 = i & 31;
    float4 h = ((const float4*)H)[i];
    float4 sc = ((const float4*)stats)[j4];
    float4 sh = ((const float4*)(stats + DIM))[j4];
    float4 o;
    o.x = h.x * sc.x + sh.x; o.y = h.y * sc.y + sh.y;
    o.z = h.z * sc.z + sh.z; o.w = h.w * sc.w + sh.w;
    ((float4*)out)[i] = o;
}

// ---------------------------------------------------------------------------
extern "C" void kernel_launch(void* const* d_in, const int* in_sizes, int n_in,
                              void* d_out, int out_size, void* d_ws,
                              size_t ws_size, hipStream_t stream) {
    (void)in_sizes; (void)n_in; (void)out_size; (void)ws_size;
    const float* x     = (const float*)d_in[0];
    const void*  eidx  = d_in[1];
    const float* W1    = (const float*)d_in[2];
    const float* b1    = (const float*)d_in[3];
    const float* W2    = (const float*)d_in[4];
    const float* b2    = (const float*)d_in[5];
    const float* gamma = (const float*)d_in[6];
    const float* beta  = (const float*)d_in[7];
    float* out = (float*)d_out;

    // bump allocator over d_ws (re-poisoned every call -> everything below is
    // fully (re)written or zeroed each launch)
    char* p = (char*)d_ws;
    auto alloc = [&](size_t bytes) {
        char* r = p;
        p += (bytes + 255) & ~(size_t)255;
        return r;
    };
    float* H        = (float*)alloc((size_t)N_NODES * DIM * 4);  // 51.2 MB
    int*   counts   = (int*)alloc((size_t)N_NODES * 4);
    int*   excl     = (int*)alloc((size_t)N_NODES * 4);
    int*   rowst    = (int*)alloc((size_t)(N_NODES + 1) * 4);
    int*   cursor   = (int*)alloc((size_t)N_NODES * 4);
    int*   bsums    = (int*)alloc(512 * 4);
    int*   cols     = (int*)alloc((size_t)N_EDGES * 4);          // 6.4 MB
    float* stats    = (float*)alloc(2 * DIM * 4);
    int*   flag     = (int*)alloc(16);

    hipMemsetAsync(counts, 0, (size_t)N_NODES * 4, stream);
    hipMemsetAsync(stats, 0, 2 * DIM * 4, stream);

    detect_dtype<<<1, 1, 0, stream>>>((const int*)eidx, flag);
    hist_kernel<<<2048, 256, 0, stream>>>(eidx, flag, counts);

    int nb = (N_NODES + 255) / 256;              // 391 <= 512
    scan_block<<<nb, 256, 0, stream>>>(counts, excl, bsums, N_NODES);
    scan_sums<<<1, 512, 0, stream>>>(bsums, nb);
    scan_add<<<nb, 256, 0, stream>>>(excl, bsums, rowst, cursor, N_NODES,
                                     N_EDGES);
    fill_kernel<<<2048, 256, 0, stream>>>(eidx, flag, cursor, cols);

    agg_kernel<<<N_NODES / 4, 256, 0, stream>>>(x, rowst, cols, H);

    gemm_kernel<true, false><<<N_NODES / 80, 256, 0, stream>>>(H, W1, b1,
                                                               nullptr);
    gemm_kernel<false, true><<<N_NODES / 80, 256, 0, stream>>>(H, W2, b2,
                                                               stats);
    finalize_stats<<<1, 128, 0, stream>>>(stats, gamma, beta);
    bn_apply<<<(N_NODES * DIM / 4) / 256, 256, 0, stream>>>(H, stats, out);
}